// Round 4
// baseline (142.124 us; speedup 1.0000x reference)
//
#include <hip/hip_runtime.h>
#include <hip/hip_bf16.h>
#include <math.h>

#define S_   128
#define A_   14
#define DIM  32
#define EDGE 128
#define NPAIR 196         // A*A
#define NPOS  42          // A*3
#define NTASK 238         // NPAIR + NPOS
#define RB 16
#define DB 40
#define PB 64
#define NCLS 441

// ---- workspace layout ----
// f32 region: G[441][32][128]
#define OFF_G     0
#define OFF_ARENA (NCLS*DIM*EDGE)     // floats; bf16 window arena starts here
// bf16 window arena (element offsets). Window = [o(32)][4 rows], rows k0-1..k0+2.
#define AR_SW   0                                   // [196][14][32][4] merged R+D, k0=1..14
#define AR_DW   (AR_SW + NPAIR*14*128)              // [196][23][32][4] D+R[15],   k0=16..38
#define AR_RSH  (AR_DW + NPAIR*23*128)              // [196][32][4]     R rows 13..15 (shell)
#define AR_DSH  (AR_RSH + NPAIR*128)                // [196][32][4]     D rows 14..16 (shell)
#define AR_PW   (AR_DSH + NPAIR*128)                // [42][62][32][4]  P,         k0=1..62
// arena total = 1,311,744 bf16 ≈ 2.62 MB; ws total ≈ 9.85 MB

#define MAXJOBS (NTASK + NPAIR)

// ---------------------------------------------------------------------------
// Build combined window tables.
// Pair blk: R[k]=(Wre_k+bre)@Wrl_blk, D[k]=(Wde_k+bde)@Wdl_blk.
//   SW windows (k0=1..14): rows of R+D        (common kf<=14 path)
//   DW windows (k0=16..38): rows of D+R[15]   (far kf>=16; rough edge folded)
//   RSH: R rows 13..15 ; DSH: D rows 14..16   (shell kf==15, two jobs)
// Pos blk: P[k]=(Wpe_k+bpe)@Wpl_a3; PW windows k0=1..62.
// Bias of emb folded into every row (sum of masked probs == m so it's exact);
// lin-layer biases added once in struct_main.
// ---------------------------------------------------------------------------
__global__ __launch_bounds__(256) void make_tables(
    const float* __restrict__ Wre, const float* __restrict__ bre,
    const float* __restrict__ Wde, const float* __restrict__ bde,
    const float* __restrict__ Wpe, const float* __restrict__ bpe,
    const float* __restrict__ Wrl, const float* __restrict__ Wdl,
    const float* __restrict__ Wpl, float* __restrict__ ws)
{
    __hip_bfloat16* AT = (__hip_bfloat16*)(ws + OFF_ARENA);
    __shared__ float sm[(RB + DB) > PB ? (RB + DB)*DIM : PB*DIM];
    const int blk = blockIdx.x;
    const int tid = threadIdx.x;

    if (blk < NPAIR) {
        const float* Wlr = Wrl + blk*DIM*DIM;
        const float* Wld = Wdl + blk*DIM*DIM;
        // sm[k*32+o]: k<16 -> R[k], k>=16 -> D[k-16]
        for (int idx = tid; idx < (RB+DB)*DIM; idx += 256) {
            int k = idx >> 5, o = idx & 31;
            bool isR = k < RB;
            int kk = isR ? k : k - RB;
            const float* We = isR ? Wre : Wde;
            const float* be = isR ? bre : bde;
            const float* Wl = isR ? Wlr : Wld;
            float a = 0.f;
            #pragma unroll 8
            for (int m = 0; m < DIM; ++m)
                a = fmaf(We[kk*DIM+m] + be[m], Wl[m*DIM+o], a);
            sm[idx] = a;
        }
        __syncthreads();
        // SW windows
        for (int idx = tid; idx < 14*128; idx += 256) {
            int w = idx >> 7, rem = idx & 127, o = rem >> 2, j = rem & 3;
            int r = w + j;
            float v = (r < RB) ? sm[r*DIM+o] + sm[(RB+r)*DIM+o] : 0.f;
            AT[AR_SW + (size_t)blk*14*128 + w*128 + rem] = __float2bfloat16(v);
        }
        // DW windows (k0 = 16+w, rows 15+w+j), D + R[15]
        for (int idx = tid; idx < 23*128; idx += 256) {
            int w = idx >> 7, rem = idx & 127, o = rem >> 2, j = rem & 3;
            int r = 15 + w + j;
            float v = (r < DB) ? sm[(RB+r)*DIM+o] + sm[(RB-1)*DIM+o] : 0.f;
            AT[AR_DW + (size_t)blk*23*128 + w*128 + rem] = __float2bfloat16(v);
        }
        // shells
        for (int idx = tid; idx < 2*128; idx += 256) {
            int half = idx >> 7, rem = idx & 127, o = rem >> 2, j = rem & 3;
            float v;
            if (half == 0) v = (j < 3) ? sm[(13+j)*DIM+o] : 0.f;           // R 13..15
            else           v = (j < 3) ? sm[(RB+14+j)*DIM+o] : 0.f;        // D 14..16
            AT[(half ? AR_DSH : AR_RSH) + blk*128 + rem] = __float2bfloat16(v);
        }
    } else {
        const int a3 = blk - NPAIR;
        const float* Wlp = Wpl + a3*DIM*DIM;
        for (int idx = tid; idx < PB*DIM; idx += 256) {
            int k = idx >> 5, o = idx & 31;
            float a = 0.f;
            #pragma unroll 8
            for (int m = 0; m < DIM; ++m)
                a = fmaf(Wpe[k*DIM+m] + bpe[m], Wlp[m*DIM+o], a);
            sm[idx] = a;
        }
        __syncthreads();
        for (int idx = tid; idx < 62*128; idx += 256) {
            int w = idx >> 7, rem = idx & 127, o = rem >> 2, j = rem & 3;
            int r = w + j;
            float v = (r < PB) ? sm[r*DIM+o] : 0.f;
            AT[AR_PW + (size_t)a3*62*128 + w*128 + rem] = __float2bfloat16(v);
        }
    }
}

// ---------------------------------------------------------------------------
// G[c][j][h] = sum_i aa_emb[c][i] * z_W[i][j][h]   (f32, one block per class)
// ---------------------------------------------------------------------------
__global__ __launch_bounds__(256) void make_G(
    const float* __restrict__ aa_emb, const float* __restrict__ zW,
    float* __restrict__ ws)
{
    const int c  = blockIdx.x;
    const int h  = threadIdx.x & (EDGE - 1);
    const int jg = threadIdx.x >> 7;          // 0..1
    float* G = ws + OFF_G + (size_t)c*DIM*EDGE;
    float acc[16];
    #pragma unroll
    for (int jj = 0; jj < 16; ++jj) acc[jj] = 0.f;
    for (int i = 0; i < DIM; ++i) {
        float a = aa_emb[c*DIM + i];
        #pragma unroll
        for (int jj = 0; jj < 16; ++jj) {
            int j = jg + jj*2;
            acc[jj] = fmaf(a, zW[(size_t)(i*DIM + j)*EDGE + h], acc[jj]);
        }
    }
    #pragma unroll
    for (int jj = 0; jj < 16; ++jj)
        G[(jg + jj*2)*EDGE + h] = acc[jj];
}

// ---------------------------------------------------------------------------
// 3-bin truncated gaussian softmax around window start k0-1; scaled by mask m.
// Max-subtraction REQUIRED: clamped edge bins can underflow all three exps.
// ---------------------------------------------------------------------------
__device__ __forceinline__ void probs3(float u, int k0, float m, float* pr)
{
    float f0 = u - (float)(k0 - 1);
    float f1 = f0 - 1.f, f2 = f0 - 2.f;
    float a0 = -12.5f * f0 * f0;
    float a1 = -12.5f * f1 * f1;
    float a2 = -12.5f * f2 * f2;
    float mx = fmaxf(a0, fmaxf(a1, a2));
    float e0 = __expf(a0 - mx), e1 = __expf(a1 - mx), e2 = __expf(a2 - mx);
    float inv = m / (e0 + e1 + e2);
    pr[0] = e0 * inv; pr[1] = e1 * inv; pr[2] = e2 * inv;
}

// ---------------------------------------------------------------------------
// Main: one block (128 thr) per (p,q).
// Phase 1: per task build job {window offset, w0,w1,w2}; rare kf==15 pair
//          tasks emit a second job, compacted deterministically via ballot.
// Phase 2: branch-free: per job one coalesced 8B uint2 -> 3 bf16 -> 3 FMA.
// Phase 3: Z[h] = z_b[h] + sum_j fd[j]*G[cls][j][h].
// ---------------------------------------------------------------------------
__global__ __launch_bounds__(128) void struct_main(
    const int*   __restrict__ aat1,
    const float* __restrict__ pos_a, const float* __restrict__ mask_a,
    const float* __restrict__ pos_b, const float* __restrict__ mask_b,
    const float* __restrict__ rots,  const float* __restrict__ trans,
    const float* __restrict__ brl,   const float* __restrict__ bdl,
    const float* __restrict__ bpl,   const float* __restrict__ zb,
    const float* __restrict__ ws,    float* __restrict__ out)
{
    const int p = blockIdx.x, q = blockIdx.y;
    __shared__ float4 jobs[MAXJOBS];
    __shared__ int    extCnt[4];
    __shared__ int    extTot;
    __shared__ float  sacc[4][DIM];
    __shared__ float  fd[DIM];
    const int t = threadIdx.x;
    const int lane = t & 63;
    const int wid  = t >> 6;

    bool   flag[2]  = {false, false};
    int    myPos[2] = {0, 0};
    float4 extraJ[2];
    extraJ[0] = make_float4(0,0,0,0); extraJ[1] = extraJ[0];

    // ---- Phase 1: build jobs ----
    #pragma unroll
    for (int it = 0; it < 2; ++it) {
        int task = t + it*128;
        bool f = false;
        if (task < NTASK) {
            float4 J;
            if (task < NPAIR) {
                int i = task / A_, j = task % A_;
                float ax = pos_a[(p*A_+i)*3+0], ay = pos_a[(p*A_+i)*3+1], az = pos_a[(p*A_+i)*3+2];
                float bx = pos_b[(q*A_+j)*3+0], by = pos_b[(q*A_+j)*3+1], bz = pos_b[(q*A_+j)*3+2];
                float dx = bx-ax, dy = by-ay, dz = bz-az;
                float d  = sqrtf(dx*dx + dy*dy + dz*dz);
                float m  = mask_a[p*A_+i] * mask_b[q*A_+j];
                float u  = (d - 2.625f) * 0.8f;      // shared off0/s for rough & dist
                int  kf  = (int)rintf(u);
                float w[3]; int off;
                if (kf <= RB-2) {                    // common: merged rough+dist
                    int kr = max(kf, 1);
                    probs3(u, kr, m, w);
                    off = AR_SW + (task*14 + (kr-1))*128;
                } else if (kf == RB-1) {             // rare shell: 2 exact jobs
                    probs3(u, RB-2, m, w);
                    off = AR_RSH + task*128;         // R rows 13..15
                    float we[3];
                    probs3(u, RB-1, m, we);
                    extraJ[it] = make_float4(
                        __int_as_float(AR_DSH + task*128),   // D rows 14..16
                        we[0], we[1], we[2]);
                    f = true;
                } else {                             // far: dist + folded rough edge
                    int kd = min(kf, DB-2);
                    probs3(u, kd, m, w);
                    off = AR_DW + (task*23 + (kd-16))*128;
                }
                J = make_float4(__int_as_float(off), w[0], w[1], w[2]);
            } else {
                int idx = task - NPAIR;
                int a = idx / 3, c = idx % 3;
                float lv = 0.f;
                #pragma unroll
                for (int jr = 0; jr < 3; ++jr)
                    lv = fmaf(rots[p*9 + jr*3 + c],
                              pos_b[(q*A_+a)*3 + jr] - trans[p*3 + jr], lv);
                float m = mask_b[p*A_+a] * mask_b[q*A_+a];
                float u = (lv + 32.f + 0.5f*(64.f/62.f)) * 0.96875f;   // 1/s = 62/64
                int kp = min(max((int)rintf(u), 1), PB-2);
                float w[3]; probs3(u, kp, m, w);
                J = make_float4(__int_as_float(AR_PW + (idx*62 + (kp-1))*128),
                                w[0], w[1], w[2]);
            }
            jobs[task] = J;
        }
        unsigned long long bal = __ballot(f);
        if (lane == 0) extCnt[it*2 + wid] = __popcll(bal);
        myPos[it] = __popcll(bal & ((1ull << lane) - 1ull));
        flag[it] = f;
    }
    __syncthreads();
    if (t == 0) {
        int s = NTASK;
        #pragma unroll
        for (int g = 0; g < 4; ++g) { int c = extCnt[g]; extCnt[g] = s; s += c; }
        extTot = s;
    }
    __syncthreads();
    #pragma unroll
    for (int it = 0; it < 2; ++it)
        if (flag[it]) jobs[extCnt[it*2 + wid] + myPos[it]] = extraJ[it];
    __syncthreads();

    // ---- Phase 2: gather-accumulate fd ----
    const int o = t & 31, seg = t >> 5;
    const ushort* Tb = (const ushort*)(ws + OFF_ARENA);
    const int nj = extTot;
    float acc = 0.f;
    for (int jb = seg; jb < nj; jb += 4) {
        float4 J = jobs[jb];
        uint2 v = *(const uint2*)(Tb + __float_as_int(J.x) + (o << 2));
        float v0 = __uint_as_float(v.x << 16);
        float v1 = __uint_as_float(v.x & 0xffff0000u);
        float v2 = __uint_as_float(v.y << 16);
        acc = fmaf(J.y, v0, acc);
        acc = fmaf(J.z, v1, acc);
        acc = fmaf(J.w, v2, acc);
    }
    sacc[seg][o] = acc;
    __syncthreads();
    if (t < DIM)
        fd[t] = sacc[0][t] + sacc[1][t] + sacc[2][t] + sacc[3][t]
              + brl[t] + bdl[t] + bpl[t];
    __syncthreads();

    // ---- Phase 3: Z row ----
    const int cls = aat1[p]*21 + aat1[q];
    const float* __restrict__ G = ws + OFF_G + (size_t)cls*DIM*EDGE + t;
    float z = zb[t];
    #pragma unroll 16
    for (int j = 0; j < DIM; ++j)
        z = fmaf(fd[j], G[j*EDGE], z);
    out[((size_t)p*S_ + q)*EDGE + t] = z;
}

extern "C" void kernel_launch(void* const* d_in, const int* in_sizes, int n_in,
                              void* d_out, int out_size, void* d_ws, size_t ws_size,
                              hipStream_t stream)
{
    const int*   aat1   = (const int*)  d_in[0];
    const float* pos_a  = (const float*)d_in[2];
    const float* mask_a = (const float*)d_in[3];
    const float* pos_b  = (const float*)d_in[4];
    const float* mask_b = (const float*)d_in[5];
    const float* aa_emb = (const float*)d_in[8];
    const float* rots   = (const float*)d_in[6];
    const float* trans  = (const float*)d_in[7];
    const float* Wre    = (const float*)d_in[9];
    const float* bre    = (const float*)d_in[10];
    const float* Wde    = (const float*)d_in[11];
    const float* bde    = (const float*)d_in[12];
    const float* Wpe    = (const float*)d_in[13];
    const float* bpe    = (const float*)d_in[14];
    const float* Wrl    = (const float*)d_in[15];
    const float* brl    = (const float*)d_in[16];
    const float* Wdl    = (const float*)d_in[17];
    const float* bdl    = (const float*)d_in[18];
    const float* Wpl    = (const float*)d_in[19];
    const float* bpl    = (const float*)d_in[20];
    const float* zW     = (const float*)d_in[21];
    const float* zb     = (const float*)d_in[22];
    float* ws   = (float*)d_ws;
    float* outp = (float*)d_out;

    hipLaunchKernelGGL(make_tables, dim3(NTASK), dim3(256), 0, stream,
                       Wre, bre, Wde, bde, Wpe, bpe, Wrl, Wdl, Wpl, ws);
    hipLaunchKernelGGL(make_G, dim3(NCLS), dim3(256), 0, stream,
                       aa_emb, zW, ws);
    hipLaunchKernelGGL(struct_main, dim3(S_, S_), dim3(128), 0, stream,
                       aat1, pos_a, mask_a, pos_b, mask_b, rots, trans,
                       brl, bdl, bpl, zb, ws, outp);
}

// Round 5
// 110.115 us; speedup vs baseline: 1.2907x; 1.2907x over previous
//
#include <hip/hip_runtime.h>
#include <hip/hip_bf16.h>
#include <math.h>

#define S_   128
#define A_   14
#define DIM  32
#define EDGE 128
#define NPAIR 196         // A*A
#define NPOS  42          // A*3
#define NTASK 238         // NPAIR + NPOS
#define RB 16
#define DB 40
#define PB 64
#define NCLS 441
#define NPID (S_*S_)

// ---- f16 arena (element offsets). Layout [t][o(32)][2]: rows 2t,2t+1 interleaved.
#define AR_SW   0                         // [196][8][64]   R+D rows 0..15
#define AR_DW   (AR_SW + NPAIR*8*64)      // [196][13][64]  D+R[15], rows 14..39 (t glob 7..19)
#define AR_RSH  (AR_DW + NPAIR*13*64)     // [196][2][64]   R rows 12..15
#define AR_DSH  (AR_RSH + NPAIR*2*64)     // [196][2][64]   D rows 14..17
#define AR_PW   (AR_DSH + NPAIR*2*64)     // [42][32][64]   P rows 0..63
#define AR_TOT  (AR_PW + NPOS*32*64)      // 399616 f16 = 800 KB

// ---- ws layout (float units)
#define OFF_G      0
#define OFF_FD     (OFF_G + NCLS*DIM*EDGE)     // fd[16384][32]
#define OFF_ORDER  (OFF_FD + NPID*DIM)         // int order[16384]
#define OFF_CSTART (OFF_ORDER + NPID)          // int cstart[442]
#define OFF_ARENA  (OFF_CSTART + 512)          // f16 arena (199808 floats)

#define MAXJOBS (NTASK + NPAIR)

typedef _Float16 h2 __attribute__((ext_vector_type(2)));

#if defined(__has_builtin)
#if __has_builtin(__builtin_amdgcn_fdot2)
#define HAVE_FDOT2 1
#endif
#endif

__device__ __forceinline__ float fdot2f(unsigned int a, unsigned int b, float c) {
    h2 ha = __builtin_bit_cast(h2, a), hb = __builtin_bit_cast(h2, b);
#ifdef HAVE_FDOT2
    return __builtin_amdgcn_fdot2(ha, hb, c, false);
#else
    return c + (float)ha[0]*(float)hb[0] + (float)ha[1]*(float)hb[1];
#endif
}

__device__ __forceinline__ unsigned int pack2(float lo, float hi) {
    _Float16 l = (_Float16)lo, h = (_Float16)hi;
    unsigned short lu = __builtin_bit_cast(unsigned short, l);
    unsigned short hu = __builtin_bit_cast(unsigned short, h);
    return (unsigned int)lu | ((unsigned int)hu << 16);
}

// ---------------------------------------------------------------------------
// Combined tables in f16 pair-interleaved form. Bias of emb folded into rows
// (sum of masked probs == m, so it's exact); lin biases added in struct_fd.
// ---------------------------------------------------------------------------
__global__ __launch_bounds__(256) void make_tables(
    const float* __restrict__ Wre, const float* __restrict__ bre,
    const float* __restrict__ Wde, const float* __restrict__ bde,
    const float* __restrict__ Wpe, const float* __restrict__ bpe,
    const float* __restrict__ Wrl, const float* __restrict__ Wdl,
    const float* __restrict__ Wpl, float* __restrict__ ws)
{
    _Float16* AT = (_Float16*)(ws + OFF_ARENA);
    __shared__ float sm[64*DIM];           // pair: rows 0..15 R, 16..55 D ; pos: 64 rows P
    const int blk = blockIdx.x;
    const int tid = threadIdx.x;

    if (blk < NPAIR) {
        const float* Wlr = Wrl + blk*DIM*DIM;
        const float* Wld = Wdl + blk*DIM*DIM;
        for (int idx = tid; idx < (RB+DB)*DIM; idx += 256) {
            int k = idx >> 5, o = idx & 31;
            bool isR = k < RB;
            int kk = isR ? k : k - RB;
            const float* We = isR ? Wre : Wde;
            const float* be = isR ? bre : bde;
            const float* Wl = isR ? Wlr : Wld;
            float a = 0.f;
            #pragma unroll 8
            for (int m = 0; m < DIM; ++m)
                a = fmaf(We[kk*DIM+m] + be[m], Wl[m*DIM+o], a);
            sm[idx] = a;
        }
        __syncthreads();
        // SW: rows 0..15 of R+D
        for (int idx = tid; idx < 8*64; idx += 256) {
            int t = idx >> 6, rem = idx & 63, o = rem >> 1, i = rem & 1;
            int r = 2*t + i;
            AT[AR_SW + blk*512 + idx] = (_Float16)(sm[r*DIM+o] + sm[(RB+r)*DIM+o]);
        }
        // DW: rows 14..39 of D + R[15]
        for (int idx = tid; idx < 13*64; idx += 256) {
            int t = idx >> 6, rem = idx & 63, o = rem >> 1, i = rem & 1;
            int r = 14 + 2*t + i;
            AT[AR_DW + blk*832 + idx] = (_Float16)(sm[(RB+r)*DIM+o] + sm[(RB-1)*DIM+o]);
        }
        // RSH: R rows 12..15 ; DSH: D rows 14..17
        for (int idx = tid; idx < 2*64; idx += 256) {
            int t = idx >> 6, rem = idx & 63, o = rem >> 1, i = rem & 1;
            AT[AR_RSH + blk*128 + idx] = (_Float16)sm[(12 + 2*t + i)*DIM + o];
            AT[AR_DSH + blk*128 + idx] = (_Float16)sm[(RB + 14 + 2*t + i)*DIM + o];
        }
    } else {
        const int a3 = blk - NPAIR;
        const float* Wlp = Wpl + a3*DIM*DIM;
        for (int idx = tid; idx < PB*DIM; idx += 256) {
            int k = idx >> 5, o = idx & 31;
            float a = 0.f;
            #pragma unroll 8
            for (int m = 0; m < DIM; ++m)
                a = fmaf(Wpe[k*DIM+m] + bpe[m], Wlp[m*DIM+o], a);
            sm[idx] = a;
        }
        __syncthreads();
        for (int idx = tid; idx < 32*64; idx += 256) {
            int t = idx >> 6, rem = idx & 63, o = rem >> 1, i = rem & 1;
            AT[AR_PW + a3*2048 + idx] = (_Float16)sm[(2*t + i)*DIM + o];
        }
    }
}

// ---------------------------------------------------------------------------
// G[c][j][h] = sum_i aa_emb[c][i] * z_W[i][j][h]   (f32, one block per class)
// ---------------------------------------------------------------------------
__global__ __launch_bounds__(256) void make_G(
    const float* __restrict__ aa_emb, const float* __restrict__ zW,
    float* __restrict__ ws)
{
    const int c  = blockIdx.x;
    const int h  = threadIdx.x & (EDGE - 1);
    const int jg = threadIdx.x >> 7;          // 0..1
    float* G = ws + OFF_G + (size_t)c*DIM*EDGE;
    float acc[16];
    #pragma unroll
    for (int jj = 0; jj < 16; ++jj) acc[jj] = 0.f;
    for (int i = 0; i < DIM; ++i) {
        float a = aa_emb[c*DIM + i];
        #pragma unroll
        for (int jj = 0; jj < 16; ++jj) {
            int j = jg + jj*2;
            acc[jj] = fmaf(a, zW[(size_t)(i*DIM + j)*EDGE + h], acc[jj]);
        }
    }
    #pragma unroll
    for (int jj = 0; jj < 16; ++jj)
        G[(jg + jj*2)*EDGE + h] = acc[jj];
}

// ---------------------------------------------------------------------------
// Counting sort of pair ids by class. Order within a class is race-dependent
// but each pair's output is computed independently -> d_out deterministic.
// ---------------------------------------------------------------------------
__global__ __launch_bounds__(1024) void sort_pairs(
    const int* __restrict__ aat1, float* __restrict__ ws)
{
    int* order  = (int*)(ws + OFF_ORDER);
    int* cstart = (int*)(ws + OFF_CSTART);
    __shared__ int hist[NCLS];
    __shared__ int offs[NCLS];
    const int tid = threadIdx.x;
    for (int c = tid; c < NCLS; c += 1024) hist[c] = 0;
    __syncthreads();
    for (int pid = tid; pid < NPID; pid += 1024) {
        int cls = aat1[pid >> 7]*21 + aat1[pid & 127];
        atomicAdd(&hist[cls], 1);
    }
    __syncthreads();
    if (tid == 0) {
        int s = 0;
        for (int c = 0; c < NCLS; ++c) { offs[c] = s; cstart[c] = s; s += hist[c]; }
        cstart[NCLS] = s;
    }
    __syncthreads();
    for (int pid = tid; pid < NPID; pid += 1024) {
        int cls = aat1[pid >> 7]*21 + aat1[pid & 127];
        int pos = atomicAdd(&offs[cls], 1);
        order[pos] = pid;
    }
}

// ---------------------------------------------------------------------------
// 3-bin truncated gaussian softmax around window start k0-1; scaled by mask m.
// Max-subtraction REQUIRED: clamped edge bins can underflow all three exps.
// ---------------------------------------------------------------------------
__device__ __forceinline__ void probs3(float u, int k0, float m, float* pr)
{
    float f0 = u - (float)(k0 - 1);
    float f1 = f0 - 1.f, f2 = f0 - 2.f;
    float a0 = -12.5f * f0 * f0;
    float a1 = -12.5f * f1 * f1;
    float a2 = -12.5f * f2 * f2;
    float mx = fmaxf(a0, fmaxf(a1, a2));
    float e0 = __expf(a0 - mx), e1 = __expf(a1 - mx), e2 = __expf(a2 - mx);
    float inv = m / (e0 + e1 + e2);
    pr[0] = e0 * inv; pr[1] = e1 * inv; pr[2] = e2 * inv;
}

// rows b..b+2 get weights w0..w2; rows pair-aligned from t0 = b>>1.
__device__ __forceinline__ void packW(const float* w, int b,
                                      unsigned int& wp0, unsigned int& wp1)
{
    if (b & 1) { wp0 = pack2(0.f, w[0]);  wp1 = pack2(w[1], w[2]); }
    else       { wp0 = pack2(w[0], w[1]); wp1 = pack2(w[2], 0.f); }
}

// ---------------------------------------------------------------------------
// struct_fd: one block (128 thr) per (p,q). Phase 1 builds jobs
// {arena elem offset, wpair0, wpair1}; kf==15 pairs emit a second job
// (ballot-compacted). Phase 2: per job per lane 2 dword loads + 2 fdot2.
// Writes fd[pid][32].
// ---------------------------------------------------------------------------
__global__ __launch_bounds__(128) void struct_fd(
    const float* __restrict__ pos_a, const float* __restrict__ mask_a,
    const float* __restrict__ pos_b, const float* __restrict__ mask_b,
    const float* __restrict__ rots,  const float* __restrict__ trans,
    const float* __restrict__ brl,   const float* __restrict__ bdl,
    const float* __restrict__ bpl,   float* __restrict__ ws)
{
    const int p = blockIdx.x, q = blockIdx.y;
    __shared__ uint4 jobs[MAXJOBS];
    __shared__ int   extCnt[4];
    __shared__ int   extTot;
    __shared__ float sacc[4][DIM];
    const int t = threadIdx.x;
    const int lane = t & 63;
    const int wid  = t >> 6;

    bool  flag[2]  = {false, false};
    int   myPos[2] = {0, 0};
    uint4 extraJ[2];
    extraJ[0] = make_uint4(0,0,0,0); extraJ[1] = extraJ[0];

    // ---- Phase 1 ----
    #pragma unroll
    for (int it = 0; it < 2; ++it) {
        int task = t + it*128;
        bool f = false;
        if (task < NTASK) {
            uint4 J;
            if (task < NPAIR) {
                int i = task / A_, j = task % A_;
                float ax = pos_a[(p*A_+i)*3+0], ay = pos_a[(p*A_+i)*3+1], az = pos_a[(p*A_+i)*3+2];
                float bx = pos_b[(q*A_+j)*3+0], by = pos_b[(q*A_+j)*3+1], bz = pos_b[(q*A_+j)*3+2];
                float dx = bx-ax, dy = by-ay, dz = bz-az;
                float d  = sqrtf(dx*dx + dy*dy + dz*dz);
                float m  = mask_a[p*A_+i] * mask_b[q*A_+j];
                float u  = (d - 2.625f) * 0.8f;      // shared off0/s for rough & dist
                int  kf  = (int)rintf(u);
                float w[3]; unsigned int off, wp0, wp1; int b;
                if (kf <= RB-2) {                    // merged rough+dist, rows 0..15
                    int k0 = max(kf, 1);
                    probs3(u, k0, m, w);
                    b = k0 - 1;
                    off = AR_SW + task*512 + (b>>1)*64;
                } else if (kf == RB-1) {             // shell: two exact jobs
                    probs3(u, RB-2, m, w);           // R rows 13..15
                    b = 13;                          // stored from row 12 (even)
                    off = AR_RSH + task*128;
                    float we[3];
                    probs3(u, RB-1, m, we);          // D rows 14..16
                    unsigned int e0, e1;
                    packW(we, 14, e0, e1);           // stored from row 14 (even)
                    extraJ[it] = make_uint4(AR_DSH + task*128, e0, e1, 0);
                    f = true;
                } else {                             // far: dist + folded rough edge
                    int kd = min(kf, DB-2);
                    probs3(u, kd, m, w);
                    b = kd - 1;                      // global rows; stored from 14
                    off = AR_DW + task*832 + ((b>>1) - 7)*64;
                }
                packW(w, b, wp0, wp1);
                J = make_uint4(off, wp0, wp1, 0);
            } else {
                int idx = task - NPAIR;
                int a = idx / 3, c = idx % 3;
                float lv = 0.f;
                #pragma unroll
                for (int jr = 0; jr < 3; ++jr)
                    lv = fmaf(rots[p*9 + jr*3 + c],
                              pos_b[(q*A_+a)*3 + jr] - trans[p*3 + jr], lv);
                float m = mask_b[p*A_+a] * mask_b[q*A_+a];
                float u = (lv + 32.f + 0.5f*(64.f/62.f)) * 0.96875f;   // 1/s = 62/64
                int kp = min(max((int)rintf(u), 1), PB-2);
                float w[3]; probs3(u, kp, m, w);
                int b = kp - 1;
                unsigned int wp0, wp1;
                packW(w, b, wp0, wp1);
                J = make_uint4(AR_PW + idx*2048 + (b>>1)*64, wp0, wp1, 0);
            }
            jobs[task] = J;
        }
        unsigned long long bal = __ballot(f);
        if (lane == 0) extCnt[it*2 + wid] = __popcll(bal);
        myPos[it] = __popcll(bal & ((1ull << lane) - 1ull));
        flag[it] = f;
    }
    __syncthreads();
    if (t == 0) {
        int s = NTASK;
        #pragma unroll
        for (int g = 0; g < 4; ++g) { int c = extCnt[g]; extCnt[g] = s; s += c; }
        extTot = s;
    }
    __syncthreads();
    #pragma unroll
    for (int it = 0; it < 2; ++it)
        if (flag[it]) jobs[extCnt[it*2 + wid] + myPos[it]] = extraJ[it];
    __syncthreads();

    // ---- Phase 2: per job: 2 dword loads + 2 fdot2 ----
    const int o = t & 31, seg = t >> 5;
    const unsigned short* Ta = (const unsigned short*)(ws + OFF_ARENA);
    const int nj = extTot;
    float acc = 0.f;
    #pragma unroll 2
    for (int jb = seg; jb < nj; jb += 4) {
        uint4 J = jobs[jb];
        const unsigned int* r0 = (const unsigned int*)(Ta + J.x + (o << 1));
        unsigned int d0 = r0[0];
        unsigned int d1 = r0[32];          // +64 f16 elements
        acc = fdot2f(d0, J.y, acc);
        acc = fdot2f(d1, J.z, acc);
    }
    sacc[seg][o] = acc;
    __syncthreads();
    if (t < DIM) {
        float v = sacc[0][t] + sacc[1][t] + sacc[2][t] + sacc[3][t]
                + brl[t] + bdl[t] + bpl[t];
        ws[OFF_FD + (p*S_ + q)*DIM + t] = v;
    }
}

// ---------------------------------------------------------------------------
// phase3: grid (441, 8). y&1 -> h-half, y>>1 -> pair stripe (stride 4).
// G[cls] half held in 32 VGPRs; fd rows broadcast-loaded.
// ---------------------------------------------------------------------------
__global__ __launch_bounds__(64) void phase3(
    const float* __restrict__ ws, const float* __restrict__ zb,
    float* __restrict__ out)
{
    const int cls = blockIdx.x;
    const int sub = blockIdx.y >> 1;
    const int h   = (blockIdx.y & 1)*64 + threadIdx.x;
    const int* order  = (const int*)(ws + OFF_ORDER);
    const int* cstart = (const int*)(ws + OFF_CSTART);
    const int s = cstart[cls], e = cstart[cls+1];
    const float* G = ws + OFF_G + (size_t)cls*DIM*EDGE + h;
    float g[DIM];
    #pragma unroll
    for (int j = 0; j < DIM; ++j) g[j] = G[j*EDGE];
    const float zbh = zb[h];
    for (int it = s + sub; it < e; it += 4) {
        int pid = order[it];
        const float* fdp = ws + OFF_FD + pid*DIM;
        float z = zbh;
        #pragma unroll
        for (int j = 0; j < DIM; ++j)
            z = fmaf(fdp[j], g[j], z);
        out[(size_t)pid*EDGE + h] = z;
    }
}

extern "C" void kernel_launch(void* const* d_in, const int* in_sizes, int n_in,
                              void* d_out, int out_size, void* d_ws, size_t ws_size,
                              hipStream_t stream)
{
    const int*   aat1   = (const int*)  d_in[0];
    const float* pos_a  = (const float*)d_in[2];
    const float* mask_a = (const float*)d_in[3];
    const float* pos_b  = (const float*)d_in[4];
    const float* mask_b = (const float*)d_in[5];
    const float* rots   = (const float*)d_in[6];
    const float* trans  = (const float*)d_in[7];
    const float* aa_emb = (const float*)d_in[8];
    const float* Wre    = (const float*)d_in[9];
    const float* bre    = (const float*)d_in[10];
    const float* Wde    = (const float*)d_in[11];
    const float* bde    = (const float*)d_in[12];
    const float* Wpe    = (const float*)d_in[13];
    const float* bpe    = (const float*)d_in[14];
    const float* Wrl    = (const float*)d_in[15];
    const float* brl    = (const float*)d_in[16];
    const float* Wdl    = (const float*)d_in[17];
    const float* bdl    = (const float*)d_in[18];
    const float* Wpl    = (const float*)d_in[19];
    const float* bpl    = (const float*)d_in[20];
    const float* zW     = (const float*)d_in[21];
    const float* zb     = (const float*)d_in[22];
    float* ws   = (float*)d_ws;
    float* outp = (float*)d_out;

    hipLaunchKernelGGL(make_tables, dim3(NTASK), dim3(256), 0, stream,
                       Wre, bre, Wde, bde, Wpe, bpe, Wrl, Wdl, Wpl, ws);
    hipLaunchKernelGGL(make_G, dim3(NCLS), dim3(256), 0, stream,
                       aa_emb, zW, ws);
    hipLaunchKernelGGL(sort_pairs, dim3(1), dim3(1024), 0, stream, aat1, ws);
    hipLaunchKernelGGL(struct_fd, dim3(S_, S_), dim3(128), 0, stream,
                       pos_a, mask_a, pos_b, mask_b, rots, trans,
                       brl, bdl, bpl, ws);
    hipLaunchKernelGGL(phase3, dim3(NCLS, 8), dim3(64), 0, stream,
                       ws, zb, outp);
}

// Round 6
// 100.101 us; speedup vs baseline: 1.4198x; 1.1000x over previous
//
#include <hip/hip_runtime.h>
#include <hip/hip_bf16.h>
#include <math.h>

#define S_   128
#define A_   14
#define DIM  32
#define EDGE 128
#define NPAIR 196         // A*A
#define NPOS  42          // A*3
#define NTASK 238         // NPAIR + NPOS
#define RB 16
#define DB 40
#define PB 64
#define NCLS 441
#define NPID (S_*S_)

// ---- f16 arena (element offsets). Layout [t][o(32)][2]: rows 2t,2t+1 interleaved.
#define AR_SW   0                         // [196][8][64]   R+D rows 0..15
#define AR_DW   (AR_SW + NPAIR*8*64)      // [196][13][64]  D+R[15], rows 14..39
#define AR_RSH  (AR_DW + NPAIR*13*64)     // [196][2][64]   R rows 12..15
#define AR_DSH  (AR_RSH + NPAIR*2*64)     // [196][2][64]   D rows 14..17
#define AR_PW   (AR_DSH + NPAIR*2*64)     // [42][32][64]   P rows 0..63
#define AR_TOT  (AR_PW + NPOS*32*64)      // 399616 f16 = 800 KB

// ---- ws layout (float units)
#define OFF_G      0
#define OFF_FD     (OFF_G + NCLS*DIM*EDGE)     // fd[16384][32]
#define OFF_ORDER  (OFF_FD + NPID*DIM)         // int order[16384]
#define OFF_CSTART (OFF_ORDER + NPID)          // int cstart[442]
#define OFF_ARENA  (OFF_CSTART + 512)          // f16 arena

#define MAXJOBS (NTASK + NPAIR)

typedef _Float16 h2 __attribute__((ext_vector_type(2)));

#if defined(__has_builtin)
#if __has_builtin(__builtin_amdgcn_fdot2)
#define HAVE_FDOT2 1
#endif
#endif

__device__ __forceinline__ float fdot2f(unsigned int a, unsigned int b, float c) {
    h2 ha = __builtin_bit_cast(h2, a), hb = __builtin_bit_cast(h2, b);
#ifdef HAVE_FDOT2
    return __builtin_amdgcn_fdot2(ha, hb, c, false);
#else
    return c + (float)ha[0]*(float)hb[0] + (float)ha[1]*(float)hb[1];
#endif
}

__device__ __forceinline__ unsigned int pack2(float lo, float hi) {
    _Float16 l = (_Float16)lo, h = (_Float16)hi;
    unsigned short lu = __builtin_bit_cast(unsigned short, l);
    unsigned short hu = __builtin_bit_cast(unsigned short, h);
    return (unsigned int)lu | ((unsigned int)hu << 16);
}

// ---------------------------------------------------------------------------
// Fused preprocessing: blocks 0..237 build f16 window tables, blocks
// 238..678 build G, block 679 does the class counting-sort. All independent.
// ---------------------------------------------------------------------------
__global__ __launch_bounds__(256) void preproc(
    const int*   __restrict__ aat1,
    const float* __restrict__ aa_emb, const float* __restrict__ zW,
    const float* __restrict__ Wre, const float* __restrict__ bre,
    const float* __restrict__ Wde, const float* __restrict__ bde,
    const float* __restrict__ Wpe, const float* __restrict__ bpe,
    const float* __restrict__ Wrl, const float* __restrict__ Wdl,
    const float* __restrict__ Wpl, float* __restrict__ ws)
{
    __shared__ float sm[64*DIM];          // 8 KB; sort aliases ints in here
    const int blk = blockIdx.x;
    const int tid = threadIdx.x;
    _Float16* AT = (_Float16*)(ws + OFF_ARENA);

    if (blk < NPAIR) {
        // ---- pair tables: R rows 0..15 (sm 0..15), D rows 0..39 (sm 16..55)
        const float* Wlr = Wrl + blk*DIM*DIM;
        const float* Wld = Wdl + blk*DIM*DIM;
        for (int idx = tid; idx < (RB+DB)*DIM; idx += 256) {
            int k = idx >> 5, o = idx & 31;
            bool isR = k < RB;
            int kk = isR ? k : k - RB;
            const float* We = isR ? Wre : Wde;
            const float* be = isR ? bre : bde;
            const float* Wl = isR ? Wlr : Wld;
            float a = 0.f;
            #pragma unroll 8
            for (int m = 0; m < DIM; ++m)
                a = fmaf(We[kk*DIM+m] + be[m], Wl[m*DIM+o], a);
            sm[idx] = a;
        }
        __syncthreads();
        for (int idx = tid; idx < 8*64; idx += 256) {        // SW: R+D rows 0..15
            int t = idx >> 6, rem = idx & 63, o = rem >> 1, i = rem & 1;
            int r = 2*t + i;
            AT[AR_SW + blk*512 + idx] = (_Float16)(sm[r*DIM+o] + sm[(RB+r)*DIM+o]);
        }
        for (int idx = tid; idx < 13*64; idx += 256) {       // DW: D rows 14..39 + R[15]
            int t = idx >> 6, rem = idx & 63, o = rem >> 1, i = rem & 1;
            int r = 14 + 2*t + i;
            AT[AR_DW + blk*832 + idx] = (_Float16)(sm[(RB+r)*DIM+o] + sm[(RB-1)*DIM+o]);
        }
        for (int idx = tid; idx < 2*64; idx += 256) {        // shells
            int t = idx >> 6, rem = idx & 63, o = rem >> 1, i = rem & 1;
            AT[AR_RSH + blk*128 + idx] = (_Float16)sm[(12 + 2*t + i)*DIM + o];
            AT[AR_DSH + blk*128 + idx] = (_Float16)sm[(RB + 14 + 2*t + i)*DIM + o];
        }
    } else if (blk < NPAIR + NPOS) {
        // ---- pos tables
        const int a3 = blk - NPAIR;
        const float* Wlp = Wpl + a3*DIM*DIM;
        for (int idx = tid; idx < PB*DIM; idx += 256) {
            int k = idx >> 5, o = idx & 31;
            float a = 0.f;
            #pragma unroll 8
            for (int m = 0; m < DIM; ++m)
                a = fmaf(Wpe[k*DIM+m] + bpe[m], Wlp[m*DIM+o], a);
            sm[idx] = a;
        }
        __syncthreads();
        for (int idx = tid; idx < 32*64; idx += 256) {
            int t = idx >> 6, rem = idx & 63, o = rem >> 1, i = rem & 1;
            AT[AR_PW + a3*2048 + idx] = (_Float16)sm[(2*t + i)*DIM + o];
        }
    } else if (blk < NTASK + NCLS) {
        // ---- G[c][j][h] = sum_i aa_emb[c][i] * zW[i][j][h]
        const int c  = blk - NTASK;
        const int h  = tid & (EDGE - 1);
        const int jg = tid >> 7;          // 0..1
        float* G = ws + OFF_G + (size_t)c*DIM*EDGE;
        float acc[16];
        #pragma unroll
        for (int jj = 0; jj < 16; ++jj) acc[jj] = 0.f;
        for (int i = 0; i < DIM; ++i) {
            float a = aa_emb[c*DIM + i];
            #pragma unroll
            for (int jj = 0; jj < 16; ++jj)
                acc[jj] = fmaf(a, zW[(size_t)(i*DIM + jg + jj*2)*EDGE + h], acc[jj]);
        }
        #pragma unroll
        for (int jj = 0; jj < 16; ++jj)
            G[(jg + jj*2)*EDGE + h] = acc[jj];
    } else {
        // ---- counting sort of pair ids by class (order within class is
        // race-dependent; per-pid outputs independent -> d_out deterministic)
        int* order  = (int*)(ws + OFF_ORDER);
        int* cstart = (int*)(ws + OFF_CSTART);
        int* hist = (int*)sm;
        int* offs = hist + NCLS;
        for (int c = tid; c < NCLS; c += 256) hist[c] = 0;
        __syncthreads();
        for (int pid = tid; pid < NPID; pid += 256) {
            int cls = aat1[pid >> 7]*21 + aat1[pid & 127];
            atomicAdd(&hist[cls], 1);
        }
        __syncthreads();
        if (tid == 0) {
            int s = 0;
            for (int c = 0; c < NCLS; ++c) { offs[c] = s; cstart[c] = s; s += hist[c]; }
            cstart[NCLS] = s;
        }
        __syncthreads();
        for (int pid = tid; pid < NPID; pid += 256) {
            int cls = aat1[pid >> 7]*21 + aat1[pid & 127];
            int pos = atomicAdd(&offs[cls], 1);
            order[pos] = pid;
        }
    }
}

// ---------------------------------------------------------------------------
// 3-bin truncated gaussian softmax around window start k0-1; scaled by mask m.
// exp2-form: exp(-12.5 f^2) = 2^(C f^2), C = -12.5*log2(e).
// Max-subtraction REQUIRED: clamped edge bins can underflow all three exps.
// ---------------------------------------------------------------------------
__device__ __forceinline__ void probs3(float u, int k0, float m, float* pr)
{
    const float C = -18.03368928f;        // -12.5 * log2(e)
    float f0 = u - (float)(k0 - 1);
    float f1 = f0 - 1.f, f2 = f0 - 2.f;
    float a0 = C * f0 * f0;
    float a1 = C * f1 * f1;
    float a2 = C * f2 * f2;
    float mx = fmaxf(a0, fmaxf(a1, a2));
    float e0 = __builtin_exp2f(a0 - mx);
    float e1 = __builtin_exp2f(a1 - mx);
    float e2 = __builtin_exp2f(a2 - mx);
    float inv = m / (e0 + e1 + e2);
    pr[0] = e0 * inv; pr[1] = e1 * inv; pr[2] = e2 * inv;
}

// rows b..b+2 get weights w0..w2; rows pair-aligned from t0 = b>>1.
__device__ __forceinline__ void packW(const float* w, int b,
                                      unsigned int& wp0, unsigned int& wp1)
{
    if (b & 1) { wp0 = pack2(0.f, w[0]);  wp1 = pack2(w[1], w[2]); }
    else       { wp0 = pack2(w[0], w[1]); wp1 = pack2(w[2], 0.f); }
}

// ---------------------------------------------------------------------------
// struct_fd: one block (256 thr) per (p,q). Phase 1: 1 task/thread builds job
// {arena elem offset, wpair0, wpair1}; kf==15 pairs emit a second job
// (ballot-compacted). Phase 2: 8 segs; per job per lane 2 dword loads + 2
// fdot2. Writes fd[pid][32].
// ---------------------------------------------------------------------------
__global__ __launch_bounds__(256) void struct_fd(
    const float* __restrict__ pos_a, const float* __restrict__ mask_a,
    const float* __restrict__ pos_b, const float* __restrict__ mask_b,
    const float* __restrict__ rots,  const float* __restrict__ trans,
    const float* __restrict__ brl,   const float* __restrict__ bdl,
    const float* __restrict__ bpl,   float* __restrict__ ws)
{
    const int p = blockIdx.x, q = blockIdx.y;
    __shared__ uint4 jobs[MAXJOBS];
    __shared__ int   extCnt[4];
    __shared__ int   extTot;
    __shared__ float sacc[8][DIM];
    const int t = threadIdx.x;
    const int lane = t & 63;
    const int wid  = t >> 6;

    bool  flag = false;
    uint4 extraJ = make_uint4(0,0,0,0);

    // ---- Phase 1 ----
    if (t < NTASK) {
        uint4 J;
        if (t < NPAIR) {
            int i = t / A_, j = t % A_;
            float ax = pos_a[(p*A_+i)*3+0], ay = pos_a[(p*A_+i)*3+1], az = pos_a[(p*A_+i)*3+2];
            float bx = pos_b[(q*A_+j)*3+0], by = pos_b[(q*A_+j)*3+1], bz = pos_b[(q*A_+j)*3+2];
            float dx = bx-ax, dy = by-ay, dz = bz-az;
            float d  = sqrtf(dx*dx + dy*dy + dz*dz);
            float m  = mask_a[p*A_+i] * mask_b[q*A_+j];
            float u  = (d - 2.625f) * 0.8f;      // shared off0/s for rough & dist
            int  kf  = (int)rintf(u);
            float w[3]; unsigned int off, wp0, wp1; int b;
            if (kf <= RB-2) {                    // merged rough+dist, rows 0..15
                int k0 = max(kf, 1);
                probs3(u, k0, m, w);
                b = k0 - 1;
                off = AR_SW + t*512 + (b>>1)*64;
            } else if (kf == RB-1) {             // shell: two exact jobs
                probs3(u, RB-2, m, w);           // R rows 13..15
                b = 13;                          // stored from row 12 (even)
                off = AR_RSH + t*128;
                float we[3];
                probs3(u, RB-1, m, we);          // D rows 14..16
                unsigned int e0, e1;
                packW(we, 14, e0, e1);           // stored from row 14 (even)
                extraJ = make_uint4(AR_DSH + t*128, e0, e1, 0);
                flag = true;
            } else {                             // far: dist + folded rough edge
                int kd = min(kf, DB-2);
                probs3(u, kd, m, w);
                b = kd - 1;                      // global rows; stored from 14
                off = AR_DW + t*832 + ((b>>1) - 7)*64;
            }
            packW(w, b, wp0, wp1);
            J = make_uint4(off, wp0, wp1, 0);
        } else {
            int idx = t - NPAIR;
            int a = idx / 3, c = idx % 3;
            float lv = 0.f;
            #pragma unroll
            for (int jr = 0; jr < 3; ++jr)
                lv = fmaf(rots[p*9 + jr*3 + c],
                          pos_b[(q*A_+a)*3 + jr] - trans[p*3 + jr], lv);
            float m = mask_b[p*A_+a] * mask_b[q*A_+a];
            float u = (lv + 32.f + 0.5f*(64.f/62.f)) * 0.96875f;   // 1/s = 62/64
            int kp = min(max((int)rintf(u), 1), PB-2);
            float w[3]; probs3(u, kp, m, w);
            int b = kp - 1;
            unsigned int wp0, wp1;
            packW(w, b, wp0, wp1);
            J = make_uint4(AR_PW + idx*2048 + (b>>1)*64, wp0, wp1, 0);
        }
        jobs[t] = J;
    }
    unsigned long long bal = __ballot(flag);
    if (lane == 0) extCnt[wid] = __popcll(bal);
    int myPos = __popcll(bal & ((1ull << lane) - 1ull));
    __syncthreads();
    if (t == 0) {
        int s = NTASK;
        #pragma unroll
        for (int g = 0; g < 4; ++g) { int c = extCnt[g]; extCnt[g] = s; s += c; }
        extTot = s;
    }
    __syncthreads();
    if (flag) jobs[extCnt[wid] + myPos] = extraJ;
    __syncthreads();

    // ---- Phase 2: per job: 2 dword loads + 2 fdot2 ----
    const int o = t & 31, seg = t >> 5;
    const unsigned short* Ta = (const unsigned short*)(ws + OFF_ARENA);
    const int nj = extTot;
    float acc = 0.f;
    #pragma unroll 4
    for (int jb = seg; jb < nj; jb += 8) {
        uint4 J = jobs[jb];
        const unsigned int* r0 = (const unsigned int*)(Ta + J.x + (o << 1));
        unsigned int d0 = r0[0];
        unsigned int d1 = r0[32];          // +64 f16 elements (offset:128)
        acc = fdot2f(d0, J.y, acc);
        acc = fdot2f(d1, J.z, acc);
    }
    sacc[seg][o] = acc;
    __syncthreads();
    if (t < DIM) {
        float v = sacc[0][t] + sacc[1][t] + sacc[2][t] + sacc[3][t]
                + sacc[4][t] + sacc[5][t] + sacc[6][t] + sacc[7][t]
                + brl[t] + bdl[t] + bpl[t];
        ws[OFF_FD + (p*S_ + q)*DIM + t] = v;
    }
}

// ---------------------------------------------------------------------------
// phase3: grid (441, 8). Block = 128 thr = full h row; stripe = blockIdx.y.
// G[cls][.][h] held in 32 VGPRs; fd rows read as float4 (uniform -> scalar).
// ---------------------------------------------------------------------------
__global__ __launch_bounds__(128) void phase3(
    const float* __restrict__ ws, const float* __restrict__ zb,
    float* __restrict__ out)
{
    const int cls    = blockIdx.x;
    const int stripe = blockIdx.y;
    const int* cstart = (const int*)(ws + OFF_CSTART);
    const int s = cstart[cls], e = cstart[cls+1];
    if (s + (int)stripe >= e) return;
    const int h = threadIdx.x;
    const int* order = (const int*)(ws + OFF_ORDER);
    const float* G = ws + OFF_G + (size_t)cls*DIM*EDGE + h;
    float g[DIM];
    #pragma unroll
    for (int j = 0; j < DIM; ++j) g[j] = G[j*EDGE];
    const float zbh = zb[h];
    for (int it = s + stripe; it < e; it += 8) {
        int pid = order[it];
        const float4* fdp = (const float4*)(ws + OFF_FD + pid*DIM);
        float z = zbh;
        #pragma unroll
        for (int j4 = 0; j4 < 8; ++j4) {
            float4 f = fdp[j4];
            z = fmaf(f.x, g[j4*4+0], z);
            z = fmaf(f.y, g[j4*4+1], z);
            z = fmaf(f.z, g[j4*4+2], z);
            z = fmaf(f.w, g[j4*4+3], z);
        }
        out[(size_t)pid*EDGE + h] = z;
    }
}

extern "C" void kernel_launch(void* const* d_in, const int* in_sizes, int n_in,
                              void* d_out, int out_size, void* d_ws, size_t ws_size,
                              hipStream_t stream)
{
    const int*   aat1   = (const int*)  d_in[0];
    const float* pos_a  = (const float*)d_in[2];
    const float* mask_a = (const float*)d_in[3];
    const float* pos_b  = (const float*)d_in[4];
    const float* mask_b = (const float*)d_in[5];
    const float* rots   = (const float*)d_in[6];
    const float* trans  = (const float*)d_in[7];
    const float* aa_emb = (const float*)d_in[8];
    const float* Wre    = (const float*)d_in[9];
    const float* bre    = (const float*)d_in[10];
    const float* Wde    = (const float*)d_in[11];
    const float* bde    = (const float*)d_in[12];
    const float* Wpe    = (const float*)d_in[13];
    const float* bpe    = (const float*)d_in[14];
    const float* Wrl    = (const float*)d_in[15];
    const float* brl    = (const float*)d_in[16];
    const float* Wdl    = (const float*)d_in[17];
    const float* bdl    = (const float*)d_in[18];
    const float* Wpl    = (const float*)d_in[19];
    const float* bpl    = (const float*)d_in[20];
    const float* zW     = (const float*)d_in[21];
    const float* zb     = (const float*)d_in[22];
    float* ws   = (float*)d_ws;
    float* outp = (float*)d_out;

    hipLaunchKernelGGL(preproc, dim3(NTASK + NCLS + 1), dim3(256), 0, stream,
                       aat1, aa_emb, zW,
                       Wre, bre, Wde, bde, Wpe, bpe, Wrl, Wdl, Wpl, ws);
    hipLaunchKernelGGL(struct_fd, dim3(S_, S_), dim3(256), 0, stream,
                       pos_a, mask_a, pos_b, mask_b, rots, trans,
                       brl, bdl, bpl, ws);
    hipLaunchKernelGGL(phase3, dim3(NCLS, 8), dim3(128), 0, stream,
                       ws, zb, outp);
}